// Round 11
// baseline (2710.327 us; speedup 1.0000x reference)
//
#include <hip/hip_runtime.h>
#include <hip/hip_bf16.h>

#define HIDDEN 3072
#define INTER  8192
#define NTOK   8192   // B*S = 4*2048

typedef __attribute__((ext_vector_type(8))) short bf16x8;
typedef __attribute__((ext_vector_type(4))) float f32x4;

__device__ __forceinline__ void gload_lds16(const void* g, void* l) {
  __builtin_amdgcn_global_load_lds(
      (const __attribute__((address_space(1))) void*)g,
      (__attribute__((address_space(3))) void*)l, 16, 0, 0);
}

__device__ __forceinline__ unsigned short f2bf(float f) {
  unsigned int u = __builtin_bit_cast(unsigned int, f);
  u += 0x7fffu + ((u >> 16) & 1u);   // round-to-nearest-even
  return (unsigned short)(u >> 16);
}

// ---------------- conversion kernels ----------------

__global__ void cvt_f32_bf16(const float* __restrict__ in,
                             unsigned short* __restrict__ out, int n4) {
  int i = blockIdx.x * blockDim.x + threadIdx.x;
  if (i >= n4) return;
  float4 v = reinterpret_cast<const float4*>(in)[i];
  ushort4 o;
  o.x = f2bf(v.x); o.y = f2bf(v.y); o.z = f2bf(v.z); o.w = f2bf(v.w);
  reinterpret_cast<ushort4*>(out)[i] = o;
}

__global__ void cvt_i32_bf16(const int* __restrict__ in,
                             unsigned short* __restrict__ out, int n4) {
  int i = blockIdx.x * blockDim.x + threadIdx.x;
  if (i >= n4) return;
  int4 v = reinterpret_cast<const int4*>(in)[i];
  ushort4 o;
  o.x = f2bf((float)v.x); o.y = f2bf((float)v.y);
  o.z = f2bf((float)v.z); o.w = f2bf((float)v.w);
  reinterpret_cast<ushort4*>(out)[i] = o;
}

// W_gu convert with gate/up row interleave at 16-row granularity:
// W'-row rowp = 32*(c>>4) + 16*u + (c&15), u=0 gate / 1 up.
__global__ void cvt_wgu_perm(const int* __restrict__ in,
                             unsigned short* __restrict__ out) {
  int i4 = blockIdx.x * blockDim.x + threadIdx.x;
  const int RW = HIDDEN / 4;   // 768 int4-groups per row
  if (i4 >= 2 * INTER * RW) return;
  int rowp = i4 / RW;
  int col4 = i4 - rowp * RW;
  int c = ((rowp >> 5) << 4) + (rowp & 15);
  int u = (rowp >> 4) & 1;
  int srow = u * INTER + c;
  int4 v = reinterpret_cast<const int4*>(in)[(size_t)srow * RW + col4];
  ushort4 o;
  o.x = f2bf((float)v.x); o.y = f2bf((float)v.y);
  o.z = f2bf((float)v.z); o.w = f2bf((float)v.w);
  reinterpret_cast<ushort4*>(out)[i4] = o;
}

// ------- GEMM1: 256x256, 16x16x32 MFMA, phase-pipelined fragments -------
// R10 structure (validated, best measured: MfmaUtil 54.5, 0 conflicts)
// + #pragma unroll 2 on the tile loop (pr becomes compile-time).
// See R10 comments for the phase/ledger derivation; unchanged here.

template<int K, int N>
__global__ __launch_bounds__(512, 2) void gemm8p(
    const unsigned short* __restrict__ A,   // [NTOK][K]
    const unsigned short* __restrict__ B,   // [N][K] (gate/up interleaved)
    const float* __restrict__ scale,
    unsigned short* __restrict__ H)
{
  constexpr int NT = K / 64;
  __shared__ __align__(16) unsigned short lds[2][2][2][256 * 32];

  const int nbn = N / 256;
  const int nwg = (NTOK / 256) * nbn;
  int bid = blockIdx.x;
  int wg = (bid & 7) * (nwg >> 3) + (bid >> 3);   // XCD-aware bijective swizzle
  const int bm = (wg / nbn) * 256;
  const int bn = (wg % nbn) * 256;

  const int tid  = threadIdx.x;
  const int lane = tid & 63;
  const int wid  = tid >> 6;
  const int wr = wid >> 2;                  // 0..1
  const int wc = wid & 3;                   // 0..3

  const int srow0 = tid >> 2;               // staging rows 0..127
  const int srow1 = 128 + (tid >> 2);       // staging rows 128..255
  const int scb   = tid & 3;

  const unsigned short* Ab = A + (size_t)bm * K;
  const unsigned short* Bb = B + (size_t)bn * K;

  auto stage = [&](const unsigned short* Gb, int op, int tt, int kh) {
    if (tt >= NT) return;
    int p = tt & 1;
    int kc = tt * 64 + kh * 32;
    unsigned short* lbase = &lds[p][op][kh][0];
    gload_lds16(Gb + (size_t)srow0 * K + kc + ((scb ^ ((srow0 >> 1) & 3)) * 8),
                lbase + (size_t)tid * 8);
    gload_lds16(Gb + (size_t)srow1 * K + kc + ((scb ^ ((srow1 >> 1) & 3)) * 8),
                lbase + (size_t)(512 + tid) * 8);
  };

  auto readA = [&](int p, int kh, int m) -> bf16x8 {
    int row = wr * 128 + m * 16 + (lane & 15);
    int cb = (lane >> 4) ^ ((row >> 1) & 3);
    return *(const bf16x8*)&lds[p][0][kh][row * 32 + cb * 8];
  };
  auto readB = [&](int p, int kh, int n) -> bf16x8 {
    int row = wc * 64 + n * 16 + (lane & 15);
    int cb = (lane >> 4) ^ ((row >> 1) & 3);
    return *(const bf16x8*)&lds[p][1][kh][row * 32 + cb * 8];
  };

  f32x4 acc[8][4] = {};
  bf16x8 aP[4], aQ[4], bP[4], bQ[4];

  // prologue: stage tile 0 (4 half-tiles); drain k0; preload aP/bP
  stage(Ab, 0, 0, 0);
  stage(Bb, 1, 0, 0);
  stage(Ab, 0, 0, 1);
  stage(Bb, 1, 0, 1);
  asm volatile("s_waitcnt vmcnt(4)" ::: "memory");
  __builtin_amdgcn_s_barrier();
#pragma unroll
  for (int m = 0; m < 4; ++m) aP[m] = readA(0, 0, m);
#pragma unroll
  for (int n = 0; n < 4; ++n) bP[n] = readB(0, 0, n);

#pragma unroll 2
  for (int t = 0; t < NT; ++t) {
    const int pr = t & 1;

    // ---- Ph0: MFMA k0/h0 (aP x bP); read A(t,k0,h1)->aQ ----
#pragma unroll
    for (int m = 0; m < 4; ++m) aQ[m] = readA(pr, 0, m + 4);
    stage(Ab, 0, t + 1, 0);
    __builtin_amdgcn_s_setprio(1);
#pragma unroll
    for (int m = 0; m < 4; ++m)
#pragma unroll
      for (int n = 0; n < 4; ++n)
        acc[m][n] = __builtin_amdgcn_mfma_f32_16x16x32_bf16(aP[m], bP[n], acc[m][n], 0, 0, 0);
    __builtin_amdgcn_s_setprio(0);

    // ---- Ph1: drain kh1(t); BAR; read A(t,k1,h0)->aP, B(t,k1)->bQ;
    //           MFMA k0/h1 (aQ x bP) ----
    if (t + 1 < NT) {
      asm volatile("s_waitcnt vmcnt(2)" ::: "memory");
    } else {
      asm volatile("s_waitcnt vmcnt(0)" ::: "memory");
    }
    __builtin_amdgcn_s_barrier();
#pragma unroll
    for (int m = 0; m < 4; ++m) aP[m] = readA(pr, 1, m);
#pragma unroll
    for (int n = 0; n < 4; ++n) bQ[n] = readB(pr, 1, n);
    stage(Bb, 1, t + 1, 0);
    __builtin_amdgcn_s_setprio(1);
#pragma unroll
    for (int m = 0; m < 4; ++m)
#pragma unroll
      for (int n = 0; n < 4; ++n)
        acc[m + 4][n] = __builtin_amdgcn_mfma_f32_16x16x32_bf16(aQ[m], bP[n], acc[m + 4][n], 0, 0, 0);
    __builtin_amdgcn_s_setprio(0);

    // ---- Ph2: read A(t,k1,h1)->aQ; MFMA k1/h0 (aP x bQ); no barrier ----
#pragma unroll
    for (int m = 0; m < 4; ++m) aQ[m] = readA(pr, 1, m + 4);
    stage(Ab, 0, t + 1, 1);
    __builtin_amdgcn_s_setprio(1);
#pragma unroll
    for (int m = 0; m < 4; ++m)
#pragma unroll
      for (int n = 0; n < 4; ++n)
        acc[m][n] = __builtin_amdgcn_mfma_f32_16x16x32_bf16(aP[m], bQ[n], acc[m][n], 0, 0, 0);
    __builtin_amdgcn_s_setprio(0);

    // ---- Ph3: drain k0(t+1); BAR; read A(t+1,k0,h0)->aP, B(t+1,k0)->bP;
    //           MFMA k1/h1 (aQ x bQ) ----
    asm volatile("s_waitcnt vmcnt(2)" ::: "memory");
    __builtin_amdgcn_s_barrier();
    if (t + 1 < NT) {
#pragma unroll
      for (int m = 0; m < 4; ++m) aP[m] = readA(pr ^ 1, 0, m);
#pragma unroll
      for (int n = 0; n < 4; ++n) bP[n] = readB(pr ^ 1, 0, n);
    }
    stage(Bb, 1, t + 1, 1);
    __builtin_amdgcn_s_setprio(1);
#pragma unroll
    for (int m = 0; m < 4; ++m)
#pragma unroll
      for (int n = 0; n < 4; ++n)
        acc[m + 4][n] = __builtin_amdgcn_mfma_f32_16x16x32_bf16(aQ[m], bQ[n], acc[m + 4][n], 0, 0, 0);
    __builtin_amdgcn_s_setprio(0);
  }

  // ---- epilogue: SwiGLU; C/D layout col=lane&15, row=(lane>>4)*4+j ----
  const int crow0 = (lane >> 4) * 4;
  const int ccol  = lane & 15;
  const int hbase = (bn >> 1) + wc * 32;
#pragma unroll
  for (int np = 0; np < 2; ++np) {
    int hcol = hbase + np * 16 + ccol;
    float sg = scale[hcol];
    float su = scale[INTER + hcol];
#pragma unroll
    for (int m = 0; m < 8; ++m) {
#pragma unroll
      for (int j = 0; j < 4; ++j) {
        int row = bm + wr * 128 + m * 16 + crow0 + j;
        float g = acc[m][2 * np + 0][j] * sg;
        float u = acc[m][2 * np + 1][j] * su;
        float s = g / (1.0f + __expf(-g));       // silu
        H[(size_t)row * INTER + hcol] = f2bf(u * s);
      }
    }
  }
}

// ------- GEMM2: 128x256 tile, grid 768 = EXACTLY 3 full CU-rounds -------
// Round-11: fixes the 384-block/256-CU imbalance (2 rounds, 2nd half-empty,
// ~25% idle) with tile geometry instead of split-K atomics (R8's overhead).
// R9-style serial-read 2-barrier loop (validated). 8 waves 2Mx4N; per wave
// 64x64 out = acc[4][4]. LDS 96KB: A[2p][2kh][128x32]=32KB, B[2p][2kh][256x32]=64KB.
//
// Asymmetric staging: A-half = 1 gload/thread (8KB), B-half = 2 (16KB).
// vmcnt ledger (loads): entering t: {A(t)k1(1), B(t)k1(2)} = 3 outstanding.
//   P1: +A(t+1)k0 -> 4.  P2: +B(t+1)k0 -> 6; W2 keeps 3 -> vmcnt(3)
//   (tail t=NT-1: stages skipped, outstanding 3 -> vmcnt(0)). BAR.
//   P3: reads k1; +A(t+1)k1 -> 4.  P4: +B(t+1)k1 -> 6; W1 keeps
//   {A(t+1)k1, B(t+1)k1} -> vmcnt(3) (tail: 0 outstanding, no-op). BAR.
// Prologue: 6 loads, need first 3 (k0 halves) -> vmcnt(3).
// WAR audit: every buffer's last reader is >=1 barrier before next stager.
// Swizzle: identical validated family (0 conflicts).

__global__ __launch_bounds__(512, 2) void gemm2k(
    const unsigned short* __restrict__ A,   // [NTOK][INTER] (hb)
    const unsigned short* __restrict__ B,   // [HIDDEN][INTER] (wd)
    const float* __restrict__ scale,        // [HIDDEN]
    float* __restrict__ O)                  // [NTOK][HIDDEN]
{
  constexpr int K = INTER;
  constexpr int NT = K / 64;                // 128
  __shared__ __align__(16) unsigned short ldsA[2][2][128 * 32];  // 32 KB
  __shared__ __align__(16) unsigned short ldsB[2][2][256 * 32];  // 64 KB

  const int nbn = HIDDEN / 256;             // 12
  const int nwg = (NTOK / 128) * nbn;       // 768 (%8==0)
  int bid = blockIdx.x;
  int wg = (bid & 7) * (nwg >> 3) + (bid >> 3);
  const int bm = (wg / nbn) * 128;
  const int bn = (wg % nbn) * 256;

  const int tid  = threadIdx.x;
  const int lane = tid & 63;
  const int wid  = tid >> 6;
  const int wr = wid >> 2;                  // 0..1 -> m-offset wr*64
  const int wc = wid & 3;                   // 0..3 -> n-offset wc*64

  const int srow0 = tid >> 2;               // 0..127
  const int srow1 = 128 + (tid >> 2);       // 128..255
  const int scb   = tid & 3;

  const unsigned short* Ab = A + (size_t)bm * K;
  const unsigned short* Bb = B + (size_t)bn * K;

  auto stageA = [&](int tt, int kh) {       // 128 rows = 1 gload/thread
    if (tt >= NT) return;
    int p = tt & 1;
    int kc = tt * 64 + kh * 32;
    gload_lds16(Ab + (size_t)srow0 * K + kc + ((scb ^ ((srow0 >> 1) & 3)) * 8),
                &ldsA[p][kh][0] + (size_t)tid * 8);
  };
  auto stageB = [&](int tt, int kh) {       // 256 rows = 2 gloads/thread
    if (tt >= NT) return;
    int p = tt & 1;
    int kc = tt * 64 + kh * 32;
    unsigned short* lbase = &ldsB[p][kh][0];
    gload_lds16(Bb + (size_t)srow0 * K + kc + ((scb ^ ((srow0 >> 1) & 3)) * 8),
                lbase + (size_t)tid * 8);
    gload_lds16(Bb + (size_t)srow1 * K + kc + ((scb ^ ((srow1 >> 1) & 3)) * 8),
                lbase + (size_t)(512 + tid) * 8);
  };

  auto readA = [&](int p, int kh, int m) -> bf16x8 {
    int row = wr * 64 + m * 16 + (lane & 15);
    int cb = (lane >> 4) ^ ((row >> 1) & 3);
    return *(const bf16x8*)&ldsA[p][kh][row * 32 + cb * 8];
  };
  auto readB = [&](int p, int kh, int n) -> bf16x8 {
    int row = wc * 64 + n * 16 + (lane & 15);
    int cb = (lane >> 4) ^ ((row >> 1) & 3);
    return *(const bf16x8*)&ldsB[p][kh][row * 32 + cb * 8];
  };

  f32x4 acc[4][4] = {};
  bf16x8 aF[4], bF[4];

  // prologue: tile 0's 4 half-tiles (6 loads); k0 halves = first 3
  stageA(0, 0);
  stageB(0, 0);
  stageA(0, 1);
  stageB(0, 1);
  asm volatile("s_waitcnt vmcnt(3)" ::: "memory");
  __builtin_amdgcn_s_barrier();

#pragma unroll 2
  for (int t = 0; t < NT; ++t) {
    const int pr = t & 1;

    // ---- P1: kh0 reads + MFMA; stage A(t+1)k0 ----
#pragma unroll
    for (int m = 0; m < 4; ++m) aF[m] = readA(pr, 0, m);
#pragma unroll
    for (int n = 0; n < 4; ++n) bF[n] = readB(pr, 0, n);
    stageA(t + 1, 0);
    __builtin_amdgcn_s_setprio(1);
#pragma unroll
    for (int m = 0; m < 4; ++m)
#pragma unroll
      for (int n = 0; n < 4; ++n)
        acc[m][n] = __builtin_amdgcn_mfma_f32_16x16x32_bf16(aF[m], bF[n], acc[m][n], 0, 0, 0);
    __builtin_amdgcn_s_setprio(0);

    // ---- P2: stage B(t+1)k0; W2 + BAR ----
    stageB(t + 1, 0);
    if (t + 1 < NT) {
      asm volatile("s_waitcnt vmcnt(3)" ::: "memory");
    } else {
      asm volatile("s_waitcnt vmcnt(0)" ::: "memory");
    }
    __builtin_amdgcn_s_barrier();

    // ---- P3: kh1 reads + MFMA; stage A(t+1)k1 ----
#pragma unroll
    for (int m = 0; m < 4; ++m) aF[m] = readA(pr, 1, m);
#pragma unroll
    for (int n = 0; n < 4; ++n) bF[n] = readB(pr, 1, n);
    stageA(t + 1, 1);
    __builtin_amdgcn_s_setprio(1);
#pragma unroll
    for (int m = 0; m < 4; ++m)
#pragma unroll
      for (int n = 0; n < 4; ++n)
        acc[m][n] = __builtin_amdgcn_mfma_f32_16x16x32_bf16(aF[m], bF[n], acc[m][n], 0, 0, 0);
    __builtin_amdgcn_s_setprio(0);

    // ---- P4: stage B(t+1)k1; W1 + BAR ----
    stageB(t + 1, 1);
    asm volatile("s_waitcnt vmcnt(3)" ::: "memory");   // no-op at tail (0 left)
    __builtin_amdgcn_s_barrier();
  }

  // ---- epilogue: C/D layout col=lane&15, row=(lane>>4)*4+j ----
  const int crow0 = (lane >> 4) * 4;
  const int ccol  = lane & 15;
#pragma unroll
  for (int n = 0; n < 4; ++n) {
    int col = bn + wc * 64 + n * 16 + ccol;
    float sc = scale[col];
#pragma unroll
    for (int m = 0; m < 4; ++m) {
#pragma unroll
      for (int j = 0; j < 4; ++j) {
        int row = bm + wr * 64 + m * 16 + crow0 + j;
        O[(size_t)row * HIDDEN + col] = acc[m][n][j] * sc;
      }
    }
  }
}

// ---------------- launch ----------------

extern "C" void kernel_launch(void* const* d_in, const int* in_sizes, int n_in,
                              void* d_out, int out_size, void* d_ws, size_t ws_size,
                              hipStream_t stream) {
  (void)in_sizes; (void)n_in; (void)out_size; (void)ws_size;

  const float* hidden = (const float*)d_in[0];   // [NTOK][HIDDEN] f32
  const int*   guq    = (const int*)d_in[1];     // [2*INTER][HIDDEN] i32
  const float* gus    = (const float*)d_in[2];   // [2*INTER]
  const int*   dwq    = (const int*)d_in[3];     // [HIDDEN][INTER] i32
  const float* dsc    = (const float*)d_in[4];   // [HIDDEN]
  float* out = (float*)d_out;

  char* ws = (char*)d_ws;
  unsigned short* xb  = (unsigned short*)(ws);                      // 50,331,648 B
  unsigned short* wgu = (unsigned short*)(ws + 50331648ull);        // 100,663,296 B (permuted)
  unsigned short* wd  = (unsigned short*)(ws + 150994944ull);       // 50,331,648 B
  unsigned short* hb  = (unsigned short*)(ws + 201326592ull);       // 134,217,728 B
  // total ws use: 335,544,320 B

  {
    int n4 = NTOK * HIDDEN / 4;
    cvt_f32_bf16<<<(n4 + 255) / 256, 256, 0, stream>>>(hidden, xb, n4);
  }
  {
    int n4 = 2 * INTER * HIDDEN / 4;
    cvt_wgu_perm<<<(n4 + 255) / 256, 256, 0, stream>>>(guq, wgu);
  }
  {
    int n4 = HIDDEN * INTER / 4;
    cvt_i32_bf16<<<(n4 + 255) / 256, 256, 0, stream>>>(dwq, wd, n4);
  }

  // GEMM1+SwiGLU: [8192 x 16384] over K=3072, writes H bf16 [8192][8192]
  gemm8p<HIDDEN, 2 * INTER>
      <<<(NTOK / 256) * (2 * INTER / 256), 512, 0, stream>>>(xb, wgu, gus, hb);
  // GEMM2: [8192 x 3072] over K=8192, 128x256 tiles, grid 768 = 3 exact rounds
  gemm2k<<<(NTOK / 128) * (HIDDEN / 256), 512, 0, stream>>>(hb, wd, dsc, out);
}

// Round 12
// 1332.404 us; speedup vs baseline: 2.0342x; 2.0342x over previous
//
#include <hip/hip_runtime.h>
#include <hip/hip_bf16.h>

#define HIDDEN 3072
#define INTER  8192
#define NTOK   8192   // B*S = 4*2048

typedef __attribute__((ext_vector_type(8))) short bf16x8;
typedef __attribute__((ext_vector_type(4))) float f32x4;

__device__ __forceinline__ void gload_lds16(const void* g, void* l) {
  __builtin_amdgcn_global_load_lds(
      (const __attribute__((address_space(1))) void*)g,
      (__attribute__((address_space(3))) void*)l, 16, 0, 0);
}

__device__ __forceinline__ unsigned short f2bf(float f) {
  unsigned int u = __builtin_bit_cast(unsigned int, f);
  u += 0x7fffu + ((u >> 16) & 1u);   // round-to-nearest-even
  return (unsigned short)(u >> 16);
}

// ---------------- conversion kernels ----------------

__global__ void cvt_f32_bf16(const float* __restrict__ in,
                             unsigned short* __restrict__ out, int n4) {
  int i = blockIdx.x * blockDim.x + threadIdx.x;
  if (i >= n4) return;
  float4 v = reinterpret_cast<const float4*>(in)[i];
  ushort4 o;
  o.x = f2bf(v.x); o.y = f2bf(v.y); o.z = f2bf(v.z); o.w = f2bf(v.w);
  reinterpret_cast<ushort4*>(out)[i] = o;
}

__global__ void cvt_i32_bf16(const int* __restrict__ in,
                             unsigned short* __restrict__ out, int n4) {
  int i = blockIdx.x * blockDim.x + threadIdx.x;
  if (i >= n4) return;
  int4 v = reinterpret_cast<const int4*>(in)[i];
  ushort4 o;
  o.x = f2bf((float)v.x); o.y = f2bf((float)v.y);
  o.z = f2bf((float)v.z); o.w = f2bf((float)v.w);
  reinterpret_cast<ushort4*>(out)[i] = o;
}

// W_gu convert with gate/up row interleave at 16-row granularity:
// W'-row rowp = 32*(c>>4) + 16*u + (c&15), u=0 gate / 1 up.
__global__ void cvt_wgu_perm(const int* __restrict__ in,
                             unsigned short* __restrict__ out) {
  int i4 = blockIdx.x * blockDim.x + threadIdx.x;
  const int RW = HIDDEN / 4;   // 768 int4-groups per row
  if (i4 >= 2 * INTER * RW) return;
  int rowp = i4 / RW;
  int col4 = i4 - rowp * RW;
  int c = ((rowp >> 5) << 4) + (rowp & 15);
  int u = (rowp >> 4) & 1;
  int srow = u * INTER + c;
  int4 v = reinterpret_cast<const int4*>(in)[(size_t)srow * RW + col4];
  ushort4 o;
  o.x = f2bf((float)v.x); o.y = f2bf((float)v.y);
  o.z = f2bf((float)v.z); o.w = f2bf((float)v.w);
  reinterpret_cast<ushort4*>(out)[i4] = o;
}

// ------- GEMM1: 256x256, 16x16x32 MFMA, phase-pipelined fragments -------
// EXACT R10 kernel (775us, MfmaUtil 54.5, 0 conflicts). NO unroll pragma:
// R11's "#pragma unroll 2" spilled the ping-pong live ranges to scratch
// (FETCH +1.2GB, WRITE +154MB, dur 2.7x) — do not re-add.
// See R10 comments for phase/ledger derivation.

template<int K, int N>
__global__ __launch_bounds__(512, 2) void gemm8p(
    const unsigned short* __restrict__ A,   // [NTOK][K]
    const unsigned short* __restrict__ B,   // [N][K] (gate/up interleaved)
    const float* __restrict__ scale,
    unsigned short* __restrict__ H)
{
  constexpr int NT = K / 64;
  __shared__ __align__(16) unsigned short lds[2][2][2][256 * 32];

  const int nbn = N / 256;
  const int nwg = (NTOK / 256) * nbn;
  int bid = blockIdx.x;
  int wg = (bid & 7) * (nwg >> 3) + (bid >> 3);   // XCD-aware bijective swizzle
  const int bm = (wg / nbn) * 256;
  const int bn = (wg % nbn) * 256;

  const int tid  = threadIdx.x;
  const int lane = tid & 63;
  const int wid  = tid >> 6;
  const int wr = wid >> 2;                  // 0..1
  const int wc = wid & 3;                   // 0..3

  const int srow0 = tid >> 2;               // staging rows 0..127
  const int srow1 = 128 + (tid >> 2);       // staging rows 128..255
  const int scb   = tid & 3;

  const unsigned short* Ab = A + (size_t)bm * K;
  const unsigned short* Bb = B + (size_t)bn * K;

  auto stage = [&](const unsigned short* Gb, int op, int tt, int kh) {
    if (tt >= NT) return;
    int p = tt & 1;
    int kc = tt * 64 + kh * 32;
    unsigned short* lbase = &lds[p][op][kh][0];
    gload_lds16(Gb + (size_t)srow0 * K + kc + ((scb ^ ((srow0 >> 1) & 3)) * 8),
                lbase + (size_t)tid * 8);
    gload_lds16(Gb + (size_t)srow1 * K + kc + ((scb ^ ((srow1 >> 1) & 3)) * 8),
                lbase + (size_t)(512 + tid) * 8);
  };

  auto readA = [&](int p, int kh, int m) -> bf16x8 {
    int row = wr * 128 + m * 16 + (lane & 15);
    int cb = (lane >> 4) ^ ((row >> 1) & 3);
    return *(const bf16x8*)&lds[p][0][kh][row * 32 + cb * 8];
  };
  auto readB = [&](int p, int kh, int n) -> bf16x8 {
    int row = wc * 64 + n * 16 + (lane & 15);
    int cb = (lane >> 4) ^ ((row >> 1) & 3);
    return *(const bf16x8*)&lds[p][1][kh][row * 32 + cb * 8];
  };

  f32x4 acc[8][4] = {};
  bf16x8 aP[4], aQ[4], bP[4], bQ[4];

  // prologue: stage tile 0 (4 half-tiles); drain k0; preload aP/bP
  stage(Ab, 0, 0, 0);
  stage(Bb, 1, 0, 0);
  stage(Ab, 0, 0, 1);
  stage(Bb, 1, 0, 1);
  asm volatile("s_waitcnt vmcnt(4)" ::: "memory");
  __builtin_amdgcn_s_barrier();
#pragma unroll
  for (int m = 0; m < 4; ++m) aP[m] = readA(0, 0, m);
#pragma unroll
  for (int n = 0; n < 4; ++n) bP[n] = readB(0, 0, n);

  for (int t = 0; t < NT; ++t) {
    const int pr = t & 1;

    // ---- Ph0: MFMA k0/h0 (aP x bP); read A(t,k0,h1)->aQ ----
#pragma unroll
    for (int m = 0; m < 4; ++m) aQ[m] = readA(pr, 0, m + 4);
    stage(Ab, 0, t + 1, 0);
    __builtin_amdgcn_s_setprio(1);
#pragma unroll
    for (int m = 0; m < 4; ++m)
#pragma unroll
      for (int n = 0; n < 4; ++n)
        acc[m][n] = __builtin_amdgcn_mfma_f32_16x16x32_bf16(aP[m], bP[n], acc[m][n], 0, 0, 0);
    __builtin_amdgcn_s_setprio(0);

    // ---- Ph1: drain kh1(t); BAR; read A(t,k1,h0)->aP, B(t,k1)->bQ;
    //           MFMA k0/h1 (aQ x bP) ----
    if (t + 1 < NT) {
      asm volatile("s_waitcnt vmcnt(2)" ::: "memory");
    } else {
      asm volatile("s_waitcnt vmcnt(0)" ::: "memory");
    }
    __builtin_amdgcn_s_barrier();
#pragma unroll
    for (int m = 0; m < 4; ++m) aP[m] = readA(pr, 1, m);
#pragma unroll
    for (int n = 0; n < 4; ++n) bQ[n] = readB(pr, 1, n);
    stage(Bb, 1, t + 1, 0);
    __builtin_amdgcn_s_setprio(1);
#pragma unroll
    for (int m = 0; m < 4; ++m)
#pragma unroll
      for (int n = 0; n < 4; ++n)
        acc[m + 4][n] = __builtin_amdgcn_mfma_f32_16x16x32_bf16(aQ[m], bP[n], acc[m + 4][n], 0, 0, 0);
    __builtin_amdgcn_s_setprio(0);

    // ---- Ph2: read A(t,k1,h1)->aQ; MFMA k1/h0 (aP x bQ); no barrier ----
#pragma unroll
    for (int m = 0; m < 4; ++m) aQ[m] = readA(pr, 1, m + 4);
    stage(Ab, 0, t + 1, 1);
    __builtin_amdgcn_s_setprio(1);
#pragma unroll
    for (int m = 0; m < 4; ++m)
#pragma unroll
      for (int n = 0; n < 4; ++n)
        acc[m][n] = __builtin_amdgcn_mfma_f32_16x16x32_bf16(aP[m], bQ[n], acc[m][n], 0, 0, 0);
    __builtin_amdgcn_s_setprio(0);

    // ---- Ph3: drain k0(t+1); BAR; read A(t+1,k0,h0)->aP, B(t+1,k0)->bP;
    //           MFMA k1/h1 (aQ x bQ) ----
    asm volatile("s_waitcnt vmcnt(2)" ::: "memory");
    __builtin_amdgcn_s_barrier();
    if (t + 1 < NT) {
#pragma unroll
      for (int m = 0; m < 4; ++m) aP[m] = readA(pr ^ 1, 0, m);
#pragma unroll
      for (int n = 0; n < 4; ++n) bP[n] = readB(pr ^ 1, 0, n);
    }
    stage(Bb, 1, t + 1, 1);
    __builtin_amdgcn_s_setprio(1);
#pragma unroll
    for (int m = 0; m < 4; ++m)
#pragma unroll
      for (int n = 0; n < 4; ++n)
        acc[m + 4][n] = __builtin_amdgcn_mfma_f32_16x16x32_bf16(aQ[m], bQ[n], acc[m + 4][n], 0, 0, 0);
    __builtin_amdgcn_s_setprio(0);
  }

  // ---- epilogue: SwiGLU; C/D layout col=lane&15, row=(lane>>4)*4+j ----
  const int crow0 = (lane >> 4) * 4;
  const int ccol  = lane & 15;
  const int hbase = (bn >> 1) + wc * 32;
#pragma unroll
  for (int np = 0; np < 2; ++np) {
    int hcol = hbase + np * 16 + ccol;
    float sg = scale[hcol];
    float su = scale[INTER + hcol];
#pragma unroll
    for (int m = 0; m < 8; ++m) {
#pragma unroll
      for (int j = 0; j < 4; ++j) {
        int row = bm + wr * 128 + m * 16 + crow0 + j;
        float g = acc[m][2 * np + 0][j] * sg;
        float u = acc[m][2 * np + 1][j] * su;
        float s = g / (1.0f + __expf(-g));       // silu
        H[(size_t)row * INTER + hcol] = f2bf(u * s);
      }
    }
  }
}

// ------- GEMM2: 128x256 tile, grid 768 = EXACTLY 3 full CU-rounds -------
// R11's geometry WITHOUT the unroll pragma (the R11 regression was the
// pragma's scratch spill, not the geometry — this round isolates it).
// R9-style serial-read 2-barrier loop. 8 waves 2Mx4N; per wave 64x64 out =
// acc[4][4]. LDS 96KB. Asymmetric staging: A-half 1 gload, B-half 2.
// vmcnt ledger: entering t: 3 outstanding {A(t)k1, B(t)k1x2}.
//   P1 +A(t+1)k0 -> 4; P2 +B(t+1)k0x2 -> 6; W2 vmcnt(3) (tail: vmcnt(0)); BAR.
//   P3 +A(t+1)k1 -> 4; P4 +B(t+1)k1x2 -> 6; W1 vmcnt(3) (tail no-op); BAR.
// Prologue 6 loads, vmcnt(3). WAR: last reader >=1 barrier before restager.

__global__ __launch_bounds__(512, 2) void gemm2k(
    const unsigned short* __restrict__ A,   // [NTOK][INTER] (hb)
    const unsigned short* __restrict__ B,   // [HIDDEN][INTER] (wd)
    const float* __restrict__ scale,        // [HIDDEN]
    float* __restrict__ O)                  // [NTOK][HIDDEN]
{
  constexpr int K = INTER;
  constexpr int NT = K / 64;                // 128
  __shared__ __align__(16) unsigned short ldsA[2][2][128 * 32];  // 32 KB
  __shared__ __align__(16) unsigned short ldsB[2][2][256 * 32];  // 64 KB

  const int nbn = HIDDEN / 256;             // 12
  const int nwg = (NTOK / 128) * nbn;       // 768 (%8==0)
  int bid = blockIdx.x;
  int wg = (bid & 7) * (nwg >> 3) + (bid >> 3);
  const int bm = (wg / nbn) * 128;
  const int bn = (wg % nbn) * 256;

  const int tid  = threadIdx.x;
  const int lane = tid & 63;
  const int wid  = tid >> 6;
  const int wr = wid >> 2;                  // 0..1 -> m-offset wr*64
  const int wc = wid & 3;                   // 0..3 -> n-offset wc*64

  const int srow0 = tid >> 2;               // 0..127
  const int srow1 = 128 + (tid >> 2);       // 128..255
  const int scb   = tid & 3;

  const unsigned short* Ab = A + (size_t)bm * K;
  const unsigned short* Bb = B + (size_t)bn * K;

  auto stageA = [&](int tt, int kh) {       // 128 rows = 1 gload/thread
    if (tt >= NT) return;
    int p = tt & 1;
    int kc = tt * 64 + kh * 32;
    gload_lds16(Ab + (size_t)srow0 * K + kc + ((scb ^ ((srow0 >> 1) & 3)) * 8),
                &ldsA[p][kh][0] + (size_t)tid * 8);
  };
  auto stageB = [&](int tt, int kh) {       // 256 rows = 2 gloads/thread
    if (tt >= NT) return;
    int p = tt & 1;
    int kc = tt * 64 + kh * 32;
    unsigned short* lbase = &ldsB[p][kh][0];
    gload_lds16(Bb + (size_t)srow0 * K + kc + ((scb ^ ((srow0 >> 1) & 3)) * 8),
                lbase + (size_t)tid * 8);
    gload_lds16(Bb + (size_t)srow1 * K + kc + ((scb ^ ((srow1 >> 1) & 3)) * 8),
                lbase + (size_t)(512 + tid) * 8);
  };

  auto readA = [&](int p, int kh, int m) -> bf16x8 {
    int row = wr * 64 + m * 16 + (lane & 15);
    int cb = (lane >> 4) ^ ((row >> 1) & 3);
    return *(const bf16x8*)&ldsA[p][kh][row * 32 + cb * 8];
  };
  auto readB = [&](int p, int kh, int n) -> bf16x8 {
    int row = wc * 64 + n * 16 + (lane & 15);
    int cb = (lane >> 4) ^ ((row >> 1) & 3);
    return *(const bf16x8*)&ldsB[p][kh][row * 32 + cb * 8];
  };

  f32x4 acc[4][4] = {};
  bf16x8 aF[4], bF[4];

  // prologue: tile 0's 4 half-tiles (6 loads); k0 halves = first 3
  stageA(0, 0);
  stageB(0, 0);
  stageA(0, 1);
  stageB(0, 1);
  asm volatile("s_waitcnt vmcnt(3)" ::: "memory");
  __builtin_amdgcn_s_barrier();

  for (int t = 0; t < NT; ++t) {
    const int pr = t & 1;

    // ---- P1: kh0 reads + MFMA; stage A(t+1)k0 ----
#pragma unroll
    for (int m = 0; m < 4; ++m) aF[m] = readA(pr, 0, m);
#pragma unroll
    for (int n = 0; n < 4; ++n) bF[n] = readB(pr, 0, n);
    stageA(t + 1, 0);
    __builtin_amdgcn_s_setprio(1);
#pragma unroll
    for (int m = 0; m < 4; ++m)
#pragma unroll
      for (int n = 0; n < 4; ++n)
        acc[m][n] = __builtin_amdgcn_mfma_f32_16x16x32_bf16(aF[m], bF[n], acc[m][n], 0, 0, 0);
    __builtin_amdgcn_s_setprio(0);

    // ---- P2: stage B(t+1)k0; W2 + BAR ----
    stageB(t + 1, 0);
    if (t + 1 < NT) {
      asm volatile("s_waitcnt vmcnt(3)" ::: "memory");
    } else {
      asm volatile("s_waitcnt vmcnt(0)" ::: "memory");
    }
    __builtin_amdgcn_s_barrier();

    // ---- P3: kh1 reads + MFMA; stage A(t+1)k1 ----
#pragma unroll
    for (int m = 0; m < 4; ++m) aF[m] = readA(pr, 1, m);
#pragma unroll
    for (int n = 0; n < 4; ++n) bF[n] = readB(pr, 1, n);
    stageA(t + 1, 1);
    __builtin_amdgcn_s_setprio(1);
#pragma unroll
    for (int m = 0; m < 4; ++m)
#pragma unroll
      for (int n = 0; n < 4; ++n)
        acc[m][n] = __builtin_amdgcn_mfma_f32_16x16x32_bf16(aF[m], bF[n], acc[m][n], 0, 0, 0);
    __builtin_amdgcn_s_setprio(0);

    // ---- P4: stage B(t+1)k1; W1 + BAR ----
    stageB(t + 1, 1);
    asm volatile("s_waitcnt vmcnt(3)" ::: "memory");   // no-op at tail (0 left)
    __builtin_amdgcn_s_barrier();
  }

  // ---- epilogue: C/D layout col=lane&15, row=(lane>>4)*4+j ----
  const int crow0 = (lane >> 4) * 4;
  const int ccol  = lane & 15;
#pragma unroll
  for (int n = 0; n < 4; ++n) {
    int col = bn + wc * 64 + n * 16 + ccol;
    float sc = scale[col];
#pragma unroll
    for (int m = 0; m < 4; ++m) {
#pragma unroll
      for (int j = 0; j < 4; ++j) {
        int row = bm + wr * 64 + m * 16 + crow0 + j;
        O[(size_t)row * HIDDEN + col] = acc[m][n][j] * sc;
      }
    }
  }
}

// ---------------- launch ----------------

extern "C" void kernel_launch(void* const* d_in, const int* in_sizes, int n_in,
                              void* d_out, int out_size, void* d_ws, size_t ws_size,
                              hipStream_t stream) {
  (void)in_sizes; (void)n_in; (void)out_size; (void)ws_size;

  const float* hidden = (const float*)d_in[0];   // [NTOK][HIDDEN] f32
  const int*   guq    = (const int*)d_in[1];     // [2*INTER][HIDDEN] i32
  const float* gus    = (const float*)d_in[2];   // [2*INTER]
  const int*   dwq    = (const int*)d_in[3];     // [HIDDEN][INTER] i32
  const float* dsc    = (const float*)d_in[4];   // [HIDDEN]
  float* out = (float*)d_out;

  char* ws = (char*)d_ws;
  unsigned short* xb  = (unsigned short*)(ws);                      // 50,331,648 B
  unsigned short* wgu = (unsigned short*)(ws + 50331648ull);        // 100,663,296 B (permuted)
  unsigned short* wd  = (unsigned short*)(ws + 150994944ull);       // 50,331,648 B
  unsigned short* hb  = (unsigned short*)(ws + 201326592ull);       // 134,217,728 B
  // total ws use: 335,544,320 B

  {
    int n4 = NTOK * HIDDEN / 4;
    cvt_f32_bf16<<<(n4 + 255) / 256, 256, 0, stream>>>(hidden, xb, n4);
  }
  {
    int n4 = 2 * INTER * HIDDEN / 4;
    cvt_wgu_perm<<<(n4 + 255) / 256, 256, 0, stream>>>(guq, wgu);
  }
  {
    int n4 = HIDDEN * INTER / 4;
    cvt_i32_bf16<<<(n4 + 255) / 256, 256, 0, stream>>>(dwq, wd, n4);
  }

  // GEMM1+SwiGLU: [8192 x 16384] over K=3072, writes H bf16 [8192][8192]
  gemm8p<HIDDEN, 2 * INTER>
      <<<(NTOK / 256) * (2 * INTER / 256), 512, 0, stream>>>(xb, wgu, gus, hb);
  // GEMM2: [8192 x 3072] over K=8192, 128x256 tiles, grid 768 = 3 exact rounds
  gemm2k<<<(NTOK / 128) * (HIDDEN / 256), 512, 0, stream>>>(hb, wd, dsc, out);
}

// Round 13
// 1251.038 us; speedup vs baseline: 2.1665x; 1.0650x over previous
//
#include <hip/hip_runtime.h>
#include <hip/hip_bf16.h>

#define HIDDEN 3072
#define INTER  8192
#define NTOK   8192   // B*S = 4*2048

typedef __attribute__((ext_vector_type(8))) short bf16x8;
typedef __attribute__((ext_vector_type(4))) float f32x4;

__device__ __forceinline__ void gload_lds16(const void* g, void* l) {
  __builtin_amdgcn_global_load_lds(
      (const __attribute__((address_space(1))) void*)g,
      (__attribute__((address_space(3))) void*)l, 16, 0, 0);
}

__device__ __forceinline__ unsigned short f2bf(float f) {
  unsigned int u = __builtin_bit_cast(unsigned int, f);
  u += 0x7fffu + ((u >> 16) & 1u);   // round-to-nearest-even
  return (unsigned short)(u >> 16);
}

// ---------------- conversion kernels ----------------

__global__ void cvt_f32_bf16(const float* __restrict__ in,
                             unsigned short* __restrict__ out, int n4) {
  int i = blockIdx.x * blockDim.x + threadIdx.x;
  if (i >= n4) return;
  float4 v = reinterpret_cast<const float4*>(in)[i];
  ushort4 o;
  o.x = f2bf(v.x); o.y = f2bf(v.y); o.z = f2bf(v.z); o.w = f2bf(v.w);
  reinterpret_cast<ushort4*>(out)[i] = o;
}

__global__ void cvt_i32_bf16(const int* __restrict__ in,
                             unsigned short* __restrict__ out, int n4) {
  int i = blockIdx.x * blockDim.x + threadIdx.x;
  if (i >= n4) return;
  int4 v = reinterpret_cast<const int4*>(in)[i];
  ushort4 o;
  o.x = f2bf((float)v.x); o.y = f2bf((float)v.y);
  o.z = f2bf((float)v.z); o.w = f2bf((float)v.w);
  reinterpret_cast<ushort4*>(out)[i] = o;
}

// W_gu convert with gate/up row interleave at 16-row granularity:
// W'-row rowp = 32*(c>>4) + 16*u + (c&15), u=0 gate / 1 up.
__global__ void cvt_wgu_perm(const int* __restrict__ in,
                             unsigned short* __restrict__ out) {
  int i4 = blockIdx.x * blockDim.x + threadIdx.x;
  const int RW = HIDDEN / 4;   // 768 int4-groups per row
  if (i4 >= 2 * INTER * RW) return;
  int rowp = i4 / RW;
  int col4 = i4 - rowp * RW;
  int c = ((rowp >> 5) << 4) + (rowp & 15);
  int u = (rowp >> 4) & 1;
  int srow = u * INTER + c;
  int4 v = reinterpret_cast<const int4*>(in)[(size_t)srow * RW + col4];
  ushort4 o;
  o.x = f2bf((float)v.x); o.y = f2bf((float)v.y);
  o.z = f2bf((float)v.z); o.w = f2bf((float)v.w);
  reinterpret_cast<ushort4*>(out)[i4] = o;
}

// ------- 256x256 GEMM, 16x16x32 MFMA, phase-pipelined fragments -------
// R10 structure (validated best: MfmaUtil 54.5, 0 conflicts) with ONE
// change (round-13 experiment): Ph1/Ph3 stage calls HOISTED above their
// vmcnt+barrier (T14 issue-early). Gives those loads ~1 extra phase in
// flight before the wait that needs them.
//
// vmcnt ledger with hoist (2 loads/stage):
//   Ph1-entry outstanding: {A(t)k1, B(t)k1, A(t+1)k0} = 6; hoisted stage
//   B(t+1)k0 -> 8; drain kh1(t) (oldest 4) -> vmcnt(4); keep 4.
//   Tail t=NT-1: stage no-op, outstanding 4 -> vmcnt(0).
//   Ph3-entry outstanding: {A(t+1)k0, B(t+1)k0, A(t+1)k1} = 6; hoisted
//   stage B(t+1)k1 -> 8; drain k0(t+1) (oldest 4) -> vmcnt(4); keep
//   {A(t+1)k1, B(t+1)k1} = 4 = steady entry state. Tail: all no-op, safe.
// WAR (hoisted writes): buffer lds[p^1][1][kh] last ds_read two tiles back
// (Ph3 of t-2), >=2 barriers before the hoisted write. Safe.
// NO unroll pragma on the t-loop (R11: scratch spill, 2.7x regression).

template<int K, int N, int MODE>
__global__ __launch_bounds__(512, 2) void gemm8p(
    const unsigned short* __restrict__ A,   // [NTOK][K]
    const unsigned short* __restrict__ B,   // [N][K]
    const float* __restrict__ scale,
    void* __restrict__ outv)
{
  constexpr int NT = K / 64;
  __shared__ __align__(16) unsigned short lds[2][2][2][256 * 32];

  const int nbn = N / 256;
  const int nwg = (NTOK / 256) * nbn;       // %8 == 0 for both instantiations
  int bid = blockIdx.x;
  int wg = (bid & 7) * (nwg >> 3) + (bid >> 3);   // XCD-aware bijective swizzle
  const int bm = (wg / nbn) * 256;
  const int bn = (wg % nbn) * 256;

  const int tid  = threadIdx.x;
  const int lane = tid & 63;
  const int wid  = tid >> 6;
  const int wr = wid >> 2;                  // 0..1
  const int wc = wid & 3;                   // 0..3

  const int srow0 = tid >> 2;               // staging rows 0..127
  const int srow1 = 128 + (tid >> 2);       // staging rows 128..255
  const int scb   = tid & 3;

  const unsigned short* Ab = A + (size_t)bm * K;
  const unsigned short* Bb = B + (size_t)bn * K;

  auto stage = [&](const unsigned short* Gb, int op, int tt, int kh) {
    if (tt >= NT) return;
    int p = tt & 1;
    int kc = tt * 64 + kh * 32;
    unsigned short* lbase = &lds[p][op][kh][0];
    gload_lds16(Gb + (size_t)srow0 * K + kc + ((scb ^ ((srow0 >> 1) & 3)) * 8),
                lbase + (size_t)tid * 8);
    gload_lds16(Gb + (size_t)srow1 * K + kc + ((scb ^ ((srow1 >> 1) & 3)) * 8),
                lbase + (size_t)(512 + tid) * 8);
  };

  auto readA = [&](int p, int kh, int m) -> bf16x8 {
    int row = wr * 128 + m * 16 + (lane & 15);
    int cb = (lane >> 4) ^ ((row >> 1) & 3);
    return *(const bf16x8*)&lds[p][0][kh][row * 32 + cb * 8];
  };
  auto readB = [&](int p, int kh, int n) -> bf16x8 {
    int row = wc * 64 + n * 16 + (lane & 15);
    int cb = (lane >> 4) ^ ((row >> 1) & 3);
    return *(const bf16x8*)&lds[p][1][kh][row * 32 + cb * 8];
  };

  f32x4 acc[8][4] = {};
  bf16x8 aP[4], aQ[4], bP[4], bQ[4];

  // prologue: stage tile 0 (4 half-tiles); drain k0 (keep k1 in flight);
  // preload aP/bP
  stage(Ab, 0, 0, 0);
  stage(Bb, 1, 0, 0);
  stage(Ab, 0, 0, 1);
  stage(Bb, 1, 0, 1);
  asm volatile("s_waitcnt vmcnt(4)" ::: "memory");
  __builtin_amdgcn_s_barrier();
#pragma unroll
  for (int m = 0; m < 4; ++m) aP[m] = readA(0, 0, m);
#pragma unroll
  for (int n = 0; n < 4; ++n) bP[n] = readB(0, 0, n);

  for (int t = 0; t < NT; ++t) {
    const int pr = t & 1;

    // ---- Ph0: MFMA k0/h0 (aP x bP); read A(t,k0,h1)->aQ ----
#pragma unroll
    for (int m = 0; m < 4; ++m) aQ[m] = readA(pr, 0, m + 4);
    stage(Ab, 0, t + 1, 0);
    __builtin_amdgcn_s_setprio(1);
#pragma unroll
    for (int m = 0; m < 4; ++m)
#pragma unroll
      for (int n = 0; n < 4; ++n)
        acc[m][n] = __builtin_amdgcn_mfma_f32_16x16x32_bf16(aP[m], bP[n], acc[m][n], 0, 0, 0);
    __builtin_amdgcn_s_setprio(0);

    // ---- Ph1: HOISTED stage B(t+1)k0; drain kh1(t); BAR;
    //           read A(t,k1,h0)->aP, B(t,k1)->bQ; MFMA k0/h1 (aQ x bP) ----
    stage(Bb, 1, t + 1, 0);
    if (t + 1 < NT) {
      asm volatile("s_waitcnt vmcnt(4)" ::: "memory");
    } else {
      asm volatile("s_waitcnt vmcnt(0)" ::: "memory");
    }
    __builtin_amdgcn_s_barrier();
#pragma unroll
    for (int m = 0; m < 4; ++m) aP[m] = readA(pr, 1, m);
#pragma unroll
    for (int n = 0; n < 4; ++n) bQ[n] = readB(pr, 1, n);
    __builtin_amdgcn_s_setprio(1);
#pragma unroll
    for (int m = 0; m < 4; ++m)
#pragma unroll
      for (int n = 0; n < 4; ++n)
        acc[m + 4][n] = __builtin_amdgcn_mfma_f32_16x16x32_bf16(aQ[m], bP[n], acc[m + 4][n], 0, 0, 0);
    __builtin_amdgcn_s_setprio(0);

    // ---- Ph2: read A(t,k1,h1)->aQ; MFMA k1/h0 (aP x bQ); no barrier ----
#pragma unroll
    for (int m = 0; m < 4; ++m) aQ[m] = readA(pr, 1, m + 4);
    stage(Ab, 0, t + 1, 1);
    __builtin_amdgcn_s_setprio(1);
#pragma unroll
    for (int m = 0; m < 4; ++m)
#pragma unroll
      for (int n = 0; n < 4; ++n)
        acc[m][n] = __builtin_amdgcn_mfma_f32_16x16x32_bf16(aP[m], bQ[n], acc[m][n], 0, 0, 0);
    __builtin_amdgcn_s_setprio(0);

    // ---- Ph3: HOISTED stage B(t+1)k1; drain k0(t+1); BAR;
    //           read A(t+1,k0,h0)->aP, B(t+1,k0)->bP; MFMA k1/h1 (aQ x bQ) ----
    stage(Bb, 1, t + 1, 1);
    asm volatile("s_waitcnt vmcnt(4)" ::: "memory");
    __builtin_amdgcn_s_barrier();
    if (t + 1 < NT) {
#pragma unroll
      for (int m = 0; m < 4; ++m) aP[m] = readA(pr ^ 1, 0, m);
#pragma unroll
      for (int n = 0; n < 4; ++n) bP[n] = readB(pr ^ 1, 0, n);
    }
    __builtin_amdgcn_s_setprio(1);
#pragma unroll
    for (int m = 0; m < 4; ++m)
#pragma unroll
      for (int n = 0; n < 4; ++n)
        acc[m + 4][n] = __builtin_amdgcn_mfma_f32_16x16x32_bf16(aQ[m], bQ[n], acc[m + 4][n], 0, 0, 0);
    __builtin_amdgcn_s_setprio(0);
  }

  // ---- epilogue: C/D layout col=lane&15, row=(lane>>4)*4+j ----
  const int crow0 = (lane >> 4) * 4;
  const int ccol  = lane & 15;
  if constexpr (MODE == 1) {
    // SwiGLU: n-frags (gate,up,gate,up) via 16-granular W interleave
    unsigned short* H = (unsigned short*)outv;     // [NTOK][INTER]
    const int hbase = (bn >> 1) + wc * 32;
#pragma unroll
    for (int np = 0; np < 2; ++np) {
      int hcol = hbase + np * 16 + ccol;
      float sg = scale[hcol];
      float su = scale[INTER + hcol];
#pragma unroll
      for (int m = 0; m < 8; ++m) {
#pragma unroll
        for (int j = 0; j < 4; ++j) {
          int row = bm + wr * 128 + m * 16 + crow0 + j;
          float g = acc[m][2 * np + 0][j] * sg;
          float u = acc[m][2 * np + 1][j] * su;
          float s = g / (1.0f + __expf(-g));       // silu
          H[(size_t)row * INTER + hcol] = f2bf(u * s);
        }
      }
    }
  } else {
    float* O = (float*)outv;                       // [NTOK][N]
#pragma unroll
    for (int n = 0; n < 4; ++n) {
      int col = bn + wc * 64 + n * 16 + ccol;
      float sc = scale[col];
#pragma unroll
      for (int m = 0; m < 8; ++m) {
#pragma unroll
        for (int j = 0; j < 4; ++j) {
          int row = bm + wr * 128 + m * 16 + crow0 + j;
          O[(size_t)row * N + col] = acc[m][n][j] * sc;
        }
      }
    }
  }
}

// ---------------- launch ----------------

extern "C" void kernel_launch(void* const* d_in, const int* in_sizes, int n_in,
                              void* d_out, int out_size, void* d_ws, size_t ws_size,
                              hipStream_t stream) {
  (void)in_sizes; (void)n_in; (void)out_size; (void)ws_size;

  const float* hidden = (const float*)d_in[0];   // [NTOK][HIDDEN] f32
  const int*   guq    = (const int*)d_in[1];     // [2*INTER][HIDDEN] i32
  const float* gus    = (const float*)d_in[2];   // [2*INTER]
  const int*   dwq    = (const int*)d_in[3];     // [HIDDEN][INTER] i32
  const float* dsc    = (const float*)d_in[4];   // [HIDDEN]
  float* out = (float*)d_out;

  char* ws = (char*)d_ws;
  unsigned short* xb  = (unsigned short*)(ws);                      // 50,331,648 B
  unsigned short* wgu = (unsigned short*)(ws + 50331648ull);        // 100,663,296 B (permuted)
  unsigned short* wd  = (unsigned short*)(ws + 150994944ull);       // 50,331,648 B
  unsigned short* hb  = (unsigned short*)(ws + 201326592ull);       // 134,217,728 B
  // total ws use: 335,544,320 B

  {
    int n4 = NTOK * HIDDEN / 4;
    cvt_f32_bf16<<<(n4 + 255) / 256, 256, 0, stream>>>(hidden, xb, n4);
  }
  {
    int n4 = 2 * INTER * HIDDEN / 4;
    cvt_wgu_perm<<<(n4 + 255) / 256, 256, 0, stream>>>(guq, wgu);
  }
  {
    int n4 = HIDDEN * INTER / 4;
    cvt_i32_bf16<<<(n4 + 255) / 256, 256, 0, stream>>>(dwq, wd, n4);
  }

  // GEMM1+SwiGLU: [8192 x 16384] over K=3072, writes H bf16 [8192][8192]
  gemm8p<HIDDEN, 2 * INTER, 1>
      <<<(NTOK / 256) * (2 * INTER / 256), 512, 0, stream>>>(xb, wgu, gus, hb);
  // GEMM2: [8192 x 3072] over K=8192, 256x256 tiles (R10 geometry), f32 store
  gemm8p<INTER, HIDDEN, 2>
      <<<(NTOK / 256) * (HIDDEN / 256), 512, 0, stream>>>(hb, wd, dsc, out);
}